// Round 10
// baseline (202.272 us; speedup 1.0000x reference)
//
#include <hip/hip_runtime.h>
#include <hip/hip_bf16.h>

#define B_SIZE 4096
#define D_SIZE 256
#define N_SIZE 8192
#define LOG2E10 14.4269504089f     // 10 * log2(e):  exp(10x) = exp2(x * LOG2E10)

#if __has_builtin(__builtin_amdgcn_exp2f)
#define FAST_EXP2(x) __builtin_amdgcn_exp2f(x)
#else
#define FAST_EXP2(x) __expf((x) * 0.69314718056f)
#endif

// s_waitcnt immediates (gfx9 encoding): vmcnt[3:0]=simm[3:0], expcnt=simm[6:4],
// lgkmcnt=simm[11:8], vmcnt[5:4]=simm[15:14]. Leave exp/lgkm unconstrained.
#define WAITCNT_VM8 0x0F78   // vmcnt <= 8
#define WAITCNT_VM0 0x0F70   // vmcnt == 0

typedef __attribute__((ext_vector_type(8))) short short8;
typedef __attribute__((ext_vector_type(4))) short short4v;
typedef __attribute__((ext_vector_type(4))) float floatx4;

// ws layout (bytes):
//       0 : float Sarr[2*8192]        (65536)  per-row full exp-sum (incl diag)
//   65536 : float lossAcc; int ticket (8)
//   66048 : int cnt[128]              (512)
//   66560 : int off[128]              (512)
//   67072 : int idxS[4096]            (16384)  row indices bucketed by class
//   83968 : float g[3][128][256]      (393216) per-class feature sums
//  524288 : bf16 featS|featT0|featT1  (3 x 2MB contiguous)

__device__ __forceinline__ void async16(void* lds, const void* g) {
    __builtin_amdgcn_global_load_lds(
        (const __attribute__((address_space(1))) unsigned int*)g,
        (__attribute__((address_space(3))) unsigned int*)lds, 16, 0, 0);
}

// Wave-per-row normalize (float4). 3072 blocks x 256. Block 0 also scatters labels.
__global__ void norm_kernel(const float* __restrict__ hs,
                            const float* __restrict__ ht0,
                            const float* __restrict__ ht1,
                            __hip_bfloat16* __restrict__ dst,
                            float* __restrict__ zero_region,
                            const int* __restrict__ labels,
                            int* __restrict__ cnt, int* __restrict__ offv,
                            int* __restrict__ idxS) {
    const int tid = threadIdx.x;
    const int wv  = tid >> 6;
    const int l   = tid & 63;
    const int gid = blockIdx.x * 256 + tid;
    if (gid < 16386) zero_region[gid] = 0.0f;   // Sarr + lossAcc + ticket

    const int row = blockIdx.x * 4 + wv;        // 0..12287
    const float* src = (row < 4096) ? (hs + row * D_SIZE)
                     : (row < 8192) ? (ht0 + (row - 4096) * D_SIZE)
                                    : (ht1 + (row - 8192) * D_SIZE);
    floatx4 x = *reinterpret_cast<const floatx4*>(src + l * 4);
    float ss = x[0] * x[0] + x[1] * x[1] + x[2] * x[2] + x[3] * x[3];
#pragma unroll
    for (int off = 32; off > 0; off >>= 1) ss += __shfl_xor(ss, off);
    float inv = 1.0f / fmaxf(sqrtf(ss), 1e-12f);
    short4v o;
#pragma unroll
    for (int k = 0; k < 4; ++k) {
        __hip_bfloat16 h = __float2bfloat16(x[k] * inv);
        o[k] = *reinterpret_cast<short*>(&h);
    }
    *reinterpret_cast<short4v*>(dst + row * D_SIZE + l * 4) = o;

    if (blockIdx.x == 0) {   // fused label scatter
        __shared__ int h[128], o2[128], ctr[128];
        if (tid < 128) { h[tid] = 0; ctr[tid] = 0; }
        __syncthreads();
        for (int i = tid; i < B_SIZE; i += 256) atomicAdd(&h[labels[i] & 127], 1);
        __syncthreads();
        if (tid == 0) {
            int s = 0;
            for (int c = 0; c < 128; ++c) { o2[c] = s; s += h[c]; }
        }
        __syncthreads();
        for (int i = tid; i < B_SIZE; i += 256) {
            int lab = labels[i] & 127;
            int pos = o2[lab] + atomicAdd(&ctr[lab], 1);
            idxS[pos] = i;
        }
        if (tid < 128) { cnt[tid] = h[tid]; offv[tid] = o2[tid]; }
    }
}

// g_c = sum_{lab_j=c} f_j per set. 384 blocks (set*128+c) x 256 threads.
__global__ void gvec_kernel(const __hip_bfloat16* __restrict__ featBase,
                            const int* __restrict__ cnt,
                            const int* __restrict__ off,
                            const int* __restrict__ idxS,
                            float* __restrict__ gOut) {
    const int c   = blockIdx.x & 127;
    const int set = blockIdx.x >> 7;
    const int tid = threadIdx.x;
    const __hip_bfloat16* f = featBase + set * B_SIZE * D_SIZE;
    __shared__ int sIdx[256];
    const int n = cnt[c], o = off[c];
    float acc = 0.0f;
    for (int base = 0; base < n; base += 256) {
        int m = n - base; if (m > 256) m = 256;
        __syncthreads();
        if (tid < m) sIdx[tid] = idxS[o + base + tid];
        __syncthreads();
        for (int k = 0; k < m; ++k)
            acc += __bfloat162float(f[sIdx[k] * D_SIZE + tid]);
    }
    gOut[set * 32768 + c * 256 + tid] = acc;
}

// Symmetric S-only sim kernel: WAVE-PRIVATE, BARRIER-FREE pipeline.
// Each wave owns 64 rows (one band; A-frags loaded once) and a contiguous
// chunk of 64-col units of the lower triangle. B staged per 16-col group into
// a private 2x8KB LDS dbuf via global_load_lds; synchronization is only
// s_waitcnt vmcnt(8/0) -- no __syncthreads anywhere.
// Schedule: per teacher, band b (0..127) gets 1+b/8 waves; 1088 waves/teacher,
// 2176 waves total = 544 blocks x 4 waves. Max 8 units (32 groups) per wave.
__global__ __launch_bounds__(256, 2)
void sim_kernel(const __hip_bfloat16* __restrict__ featS,
                const __hip_bfloat16* __restrict__ featT0,
                const __hip_bfloat16* __restrict__ featT1,
                float* __restrict__ Sarr) {
    __shared__ __align__(16) unsigned char sB[4][2][8192];   // [wave][buf][16 cols]

    const int tid  = threadIdx.x;
    const int w    = tid >> 6;
    const int l    = tid & 63;
    const int quad = l >> 4;
    const int lcol = l & 15;

    const int W   = blockIdx.x * 4 + w;      // 0..2175
    const int t   = W >= 1088;
    const int wid = W - t * 1088;            // 0..1087

    // octave k: bands 8k..8k+7 each get k+1 waves; C(k) = 4k(k+1)
    int k = 0;
    while (4 * (k + 1) * (k + 2) <= wid) ++k;
    const int rem   = wid - 4 * k * (k + 1);
    const int band  = 8 * k + rem / (k + 1);
    const int chunk = rem % (k + 1);
    const int units = band + 1;                        // 64-col units in this band
    const int per   = (units + k) / (k + 1);           // ceil(units/(k+1)) <= 8
    const int u0    = chunk * per;
    const int u1    = (u0 + per < units) ? (u0 + per) : units;
    const int ng    = (u1 - u0) * 4;                   // 16-col groups, >= 4

    const __hip_bfloat16* featT = t ? featT1 : featT0;
    const int row0 = band * 64;

    // A fragments: 4 row-tiles x 8 k-steps (128 VGPR), loaded ONCE per wave
    short8 af[4][8];
#pragma unroll
    for (int rt = 0; rt < 4; ++rt) {
        int arow = row0 + rt * 16 + lcol;
        const __hip_bfloat16* ap = (arow < B_SIZE) ? featS + arow * D_SIZE
                                                   : featT + (arow - B_SIZE) * D_SIZE;
#pragma unroll
        for (int ks = 0; ks < 8; ++ks)
            af[rt][ks] = *reinterpret_cast<const short8*>(ap + ks * 32 + quad * 8);
    }

    // stage one 16-col group (8KB) into private buffer buf; lane l fetches
    // col cb+(l&15), k-bytes (l>>4)*16 + ks*64 -> LDS base + ks*1024 + l*16
    auto stage = [&](int buf, int cb) {
        const __hip_bfloat16* cp = (cb < B_SIZE) ? featS + cb * D_SIZE
                                                 : featT + (cb - B_SIZE) * D_SIZE;
        const char* gp = (const char*)cp + (l & 15) * 512 + (l >> 4) * 16;
        unsigned char* lp = &sB[w][buf][0];
#pragma unroll
        for (int ks = 0; ks < 8; ++ks)
            async16(lp + ks * 1024, gp + ks * 64);
    };

    float Sp[4][4];
#pragma unroll
    for (int rt = 0; rt < 4; ++rt)
#pragma unroll
        for (int r = 0; r < 4; ++r) Sp[rt][r] = 0.0f;

    stage(0, u0 * 64);   // first group

    for (int gi = 0; gi < ng; ++gi) {
        const int unit = u0 + (gi >> 2);
        const int cb   = unit * 64 + (gi & 3) * 16;
        const int buf  = gi & 1;

        if (gi + 1 < ng) {
            const int unit2 = u0 + ((gi + 1) >> 2);
            stage(buf ^ 1, unit2 * 64 + ((gi + 1) & 3) * 16);
            __builtin_amdgcn_s_waitcnt(WAITCNT_VM8);   // group gi staged
        } else {
            __builtin_amdgcn_s_waitcnt(WAITCNT_VM0);
        }

        floatx4 acc[4];
#pragma unroll
        for (int rt = 0; rt < 4; ++rt) acc[rt] = floatx4{0.f, 0.f, 0.f, 0.f};

#pragma unroll
        for (int ks = 0; ks < 8; ++ks) {
            short8 bf = *reinterpret_cast<const short8*>(&sB[w][buf][ks * 1024 + l * 16]);
#pragma unroll
            for (int rt = 0; rt < 4; ++rt)
                acc[rt] = __builtin_amdgcn_mfma_f32_16x16x32_bf16(af[rt][ks], bf, acc[rt], 0, 0, 0);
        }

        float csum = 0.0f;
#pragma unroll
        for (int rt = 0; rt < 4; ++rt)
#pragma unroll
            for (int r = 0; r < 4; ++r) {
                float e = FAST_EXP2(acc[rt][r] * LOG2E10);
                Sp[rt][r] += e;
                csum += e;
            }

        if (unit != band) {   // below-diag: mirror to column row-sums
            csum += __shfl_xor(csum, 16);
            csum += __shfl_xor(csum, 32);
            if (quad == 0)
                atomicAdd(&Sarr[t * N_SIZE + cb + lcol], csum);
        }
    }

    // row-sum flush: reduce over the 16 col-lanes of each quad
#pragma unroll
    for (int rt = 0; rt < 4; ++rt)
#pragma unroll
        for (int r = 0; r < 4; ++r) {
#pragma unroll
            for (int m = 1; m < 16; m <<= 1) Sp[rt][r] += __shfl_xor(Sp[rt][r], m);
        }
    if (lcol == 0) {
#pragma unroll
        for (int rt = 0; rt < 4; ++rt)
#pragma unroll
            for (int r = 0; r < 4; ++r) {
                int row = row0 + rt * 16 + quad * 4 + r;
                atomicAdd(&Sarr[t * N_SIZE + row], Sp[rt][r]);
            }
    }
}

// Per-row stats + final loss. 512 blocks x 256; wave handles 8 rows.
__global__ void rowstat_kernel(const __hip_bfloat16* __restrict__ featS,
                               const __hip_bfloat16* __restrict__ featT0,
                               const __hip_bfloat16* __restrict__ featT1,
                               const int* __restrict__ labels,
                               const float* __restrict__ gAll,
                               const int* __restrict__ cnt,
                               const float* __restrict__ Sarr,
                               float* __restrict__ lossAcc,
                               int* __restrict__ ticket,
                               float* __restrict__ out) {
    __shared__ float wpart[4];
    const int tid = threadIdx.x;
    const int wv  = tid >> 6;
    const int l   = tid & 63;
    const int waveid = blockIdx.x * 4 + wv;   // 0..2047
    float psum = 0.0f;

    for (int it = 0; it < 8; ++it) {
        int R = waveid * 8 + it;              // 0..16383
        int t = R >> 13;
        int i = R & (N_SIZE - 1);
        const __hip_bfloat16* f = (i < B_SIZE) ? featS + i * D_SIZE
                                : (t ? featT1 : featT0) + (i - B_SIZE) * D_SIZE;
        int lab = labels[i & (B_SIZE - 1)] & 127;
        short4v fb = *reinterpret_cast<const short4v*>(f + l * 4);
        float fx[4];
#pragma unroll
        for (int k = 0; k < 4; ++k) {
            unsigned int u = ((unsigned int)(unsigned short)fb[k]) << 16;
            fx[k] = __uint_as_float(u);
        }
        const float* gS = gAll + lab * 256 + l * 4;
        const float* gT = gAll + (1 + t) * 32768 + lab * 256 + l * 4;
        float dot = 0.f, aii = 0.f;
#pragma unroll
        for (int k = 0; k < 4; ++k) {
            dot += fx[k] * (gS[k] + gT[k]);
            aii += fx[k] * fx[k];
        }
#pragma unroll
        for (int m = 1; m < 64; m <<= 1) {
            dot += __shfl_xor(dot, m);
            aii += __shfl_xor(aii, m);
        }
        if (l == 0) {
            float S = Sarr[t * N_SIZE + i];
            float M = 2.0f * (float)cnt[lab] - 1.0f;
            float E = FAST_EXP2(LOG2E10 * aii);
            psum += logf(S - E) - 10.0f * (dot - aii) / M;
        }
    }
    if (l == 0) wpart[wv] = psum;
    __syncthreads();
    if (tid == 0) {
        atomicAdd(lossAcc, wpart[0] + wpart[1] + wpart[2] + wpart[3]);
        __threadfence();
        if (atomicAdd(ticket, 1) == 511) {
            float tot = atomicAdd(lossAcc, 0.0f);
            out[0] = tot / 16384.0f;
        }
    }
}

extern "C" void kernel_launch(void* const* d_in, const int* in_sizes, int n_in,
                              void* d_out, int out_size, void* d_ws, size_t ws_size,
                              hipStream_t stream) {
    const float* hs     = (const float*)d_in[0];
    const float* ht0    = (const float*)d_in[1];
    const float* ht1    = (const float*)d_in[2];
    const int*   labels = (const int*)d_in[3];

    char* ws = (char*)d_ws;
    float* Sarr    = (float*)(ws);
    float* lossAcc = (float*)(ws + 65536);
    int*   ticket  = (int*)(ws + 65540);
    int*   cnt     = (int*)(ws + 66048);
    int*   offv    = (int*)(ws + 66560);
    int*   idxS    = (int*)(ws + 67072);
    float* gAll    = (float*)(ws + 83968);
    __hip_bfloat16* featS  = (__hip_bfloat16*)(ws + 524288);
    __hip_bfloat16* featT0 = (__hip_bfloat16*)(ws + 524288 + 2097152);
    __hip_bfloat16* featT1 = (__hip_bfloat16*)(ws + 524288 + 2 * 2097152);

    norm_kernel<<<3072, 256, 0, stream>>>(hs, ht0, ht1, featS, (float*)ws,
                                          labels, cnt, offv, idxS);
    gvec_kernel<<<384, 256, 0, stream>>>(featS, cnt, offv, idxS, gAll);
    sim_kernel<<<544, 256, 0, stream>>>(featS, featT0, featT1, Sarr);
    rowstat_kernel<<<512, 256, 0, stream>>>(featS, featT0, featT1, labels, gAll, cnt,
                                            Sarr, lossAcc, ticket, (float*)d_out);
}

// Round 11
// 167.167 us; speedup vs baseline: 1.2100x; 1.2100x over previous
//
#include <hip/hip_runtime.h>
#include <hip/hip_bf16.h>

#define B_SIZE 4096
#define D_SIZE 256
#define N_SIZE 8192
#define LOG2E10 14.4269504089f     // 10 * log2(e):  exp(10x) = exp2(x * LOG2E10)

#if __has_builtin(__builtin_amdgcn_exp2f)
#define FAST_EXP2(x) __builtin_amdgcn_exp2f(x)
#else
#define FAST_EXP2(x) exp2f(x)
#endif

typedef __attribute__((ext_vector_type(8))) short short8;
typedef __attribute__((ext_vector_type(4))) short short4v;
typedef __attribute__((ext_vector_type(4))) float floatx4;

// ws layout (bytes):
//       0 : float Sarr[2*8192]        (65536)  per-row full exp-sum (incl diag)
//   65536 : float lossAcc; int ticket (8)
//  524288 : bf16 featS|featT0|featT1  (3 x 2MB contiguous)

__device__ __forceinline__ void async16(void* lds, const void* g) {
    __builtin_amdgcn_global_load_lds(
        (const __attribute__((address_space(1))) unsigned int*)g,
        (__attribute__((address_space(3))) unsigned int*)lds, 16, 0, 0);
}

// q in [0,528) -> (R,C) with 0 <= C <= R <= 31
__device__ __forceinline__ void pair_from_q(int q, int& R, int& C) {
    int r = (int)((1.0f + sqrtf(1.0f + 8.0f * (float)q)) * 0.5f);
    while (r * (r + 1) / 2 > q) --r;
    while ((r + 1) * (r + 2) / 2 <= q) ++r;
    R = r; C = q - r * (r + 1) / 2;
}

// Wave-per-row normalize (float4). 3072 blocks x 256.
__global__ void norm_kernel(const float* __restrict__ hs,
                            const float* __restrict__ ht0,
                            const float* __restrict__ ht1,
                            __hip_bfloat16* __restrict__ dst,
                            float* __restrict__ zero_region) {
    const int tid = threadIdx.x;
    const int wv  = tid >> 6;
    const int l   = tid & 63;
    const int gid = blockIdx.x * 256 + tid;
    if (gid < 16386) zero_region[gid] = 0.0f;   // Sarr + lossAcc + ticket

    const int row = blockIdx.x * 4 + wv;        // 0..12287
    const float* src = (row < 4096) ? (hs + row * D_SIZE)
                     : (row < 8192) ? (ht0 + (row - 4096) * D_SIZE)
                                    : (ht1 + (row - 8192) * D_SIZE);
    floatx4 x = *reinterpret_cast<const floatx4*>(src + l * 4);
    float ss = x[0] * x[0] + x[1] * x[1] + x[2] * x[2] + x[3] * x[3];
#pragma unroll
    for (int off = 32; off > 0; off >>= 1) ss += __shfl_xor(ss, off);
    float inv = 1.0f / fmaxf(sqrtf(ss), 1e-12f);
    short4v o;
#pragma unroll
    for (int k = 0; k < 4; ++k) {
        __hip_bfloat16 h = __float2bfloat16(x[k] * inv);
        o[k] = *reinterpret_cast<short*>(&h);
    }
    *reinterpret_cast<short4v*>(dst + row * D_SIZE + l * 4) = o;
}

// Symmetric S-only sim kernel (R7 structure, fast exp).
// grid (528 lower-tri (R,C) pairs incl diagonal, 2 teachers), 256 threads.
// Block: rows [256R,256R+256), 4 waves x 64 rows; cols [256C,256C+256) in 4
// 64-col LDS-staged groups (dbuf, MFMA-fragment order, conflict-free).
__global__ __launch_bounds__(256, 2)
void sim_kernel(const __hip_bfloat16* __restrict__ featS,
                const __hip_bfloat16* __restrict__ featT0,
                const __hip_bfloat16* __restrict__ featT1,
                float* __restrict__ Sarr) {
    __shared__ __align__(16) unsigned char sB[2][32768];

    const int p = blockIdx.x;
    const int t = blockIdx.y;
    const __hip_bfloat16* featT = t ? featT1 : featT0;

    int R, C;
    pair_from_q(p, R, C);

    const int tid  = threadIdx.x;
    const int w    = tid >> 6;
    const int l    = tid & 63;
    const int quad = l >> 4;
    const int lcol = l & 15;
    const int row_base = R * 256 + w * 64;

    // A fragments: 4 row-tiles x 8 k-steps, register resident
    short8 af[4][8];
#pragma unroll
    for (int rt = 0; rt < 4; ++rt) {
        int arow = row_base + rt * 16 + lcol;
        const __hip_bfloat16* ap = (arow < B_SIZE) ? featS + arow * D_SIZE
                                                   : featT + (arow - B_SIZE) * D_SIZE;
#pragma unroll
        for (int ks = 0; ks < 8; ++ks)
            af[rt][ks] = *reinterpret_cast<const short8*>(ap + ks * 32 + quad * 8);
    }

    float Sp[4][4];
#pragma unroll
    for (int rt = 0; rt < 4; ++rt)
#pragma unroll
        for (int r = 0; r < 4; ++r) Sp[rt][r] = 0.0f;

    const int col0 = C * 256;

    auto stage = [&](int b, int cb) {
        int tb = cb + w * 16;
        const __hip_bfloat16* cp = (tb < B_SIZE) ? featS + tb * D_SIZE
                                                 : featT + (tb - B_SIZE) * D_SIZE;
        const char* gp = (const char*)cp + (l & 15) * 512 + (l >> 4) * 16;
        unsigned char* lp = &sB[b][w * 8192];
#pragma unroll
        for (int ks = 0; ks < 8; ++ks)
            async16(lp + ks * 1024, gp + ks * 64);
    };

    stage(0, col0);

    for (int g = 0; g < 4; ++g) {
        const int buf = g & 1;
        __syncthreads();                               // drains DMA for buf
        if (g + 1 < 4) stage(buf ^ 1, col0 + (g + 1) * 64);

        const int gcol = col0 + g * 64;
        if (gcol > row_base) continue;                 // above diagonal: skip
        const bool dg = (gcol == row_base);

        float Cp[4] = {0.f, 0.f, 0.f, 0.f};
#pragma unroll
        for (int up = 0; up < 2; ++up) {
            floatx4 acc[2][4];
#pragma unroll
            for (int j = 0; j < 2; ++j)
#pragma unroll
                for (int rt = 0; rt < 4; ++rt) acc[j][rt] = floatx4{0.f, 0.f, 0.f, 0.f};

#pragma unroll
            for (int ks = 0; ks < 8; ++ks) {
                short8 bf[2];
#pragma unroll
                for (int j = 0; j < 2; ++j)
                    bf[j] = *reinterpret_cast<const short8*>(
                        &sB[buf][(up * 2 + j) * 8192 + ks * 1024 + l * 16]);
#pragma unroll
                for (int j = 0; j < 2; ++j)
#pragma unroll
                    for (int rt = 0; rt < 4; ++rt)
                        acc[j][rt] = __builtin_amdgcn_mfma_f32_16x16x32_bf16(
                            af[rt][ks], bf[j], acc[j][rt], 0, 0, 0);
            }
#pragma unroll
            for (int j = 0; j < 2; ++j)
#pragma unroll
                for (int rt = 0; rt < 4; ++rt)
#pragma unroll
                    for (int r = 0; r < 4; ++r) {
                        float e = FAST_EXP2(acc[j][rt][r] * LOG2E10);
                        Sp[rt][r] += e;
                        Cp[up * 2 + j] += e;
                    }
        }

        if (!dg) {   // symmetric contribution: col j += sum over this tile's rows
#pragma unroll
            for (int u = 0; u < 4; ++u) {
                Cp[u] += __shfl_xor(Cp[u], 16);
                Cp[u] += __shfl_xor(Cp[u], 32);
            }
            if (quad == 0) {
#pragma unroll
                for (int u = 0; u < 4; ++u)
                    atomicAdd(&Sarr[t * N_SIZE + gcol + u * 16 + lcol], Cp[u]);
            }
        }
    }

    // row-sum flush: reduce over the 16 col-lanes of each quad
#pragma unroll
    for (int rt = 0; rt < 4; ++rt)
#pragma unroll
        for (int r = 0; r < 4; ++r) {
#pragma unroll
            for (int m = 1; m < 16; m <<= 1) Sp[rt][r] += __shfl_xor(Sp[rt][r], m);
        }
    if (lcol == 0) {
#pragma unroll
        for (int rt = 0; rt < 4; ++rt)
#pragma unroll
            for (int r = 0; r < 4; ++r) {
                int row = row_base + rt * 16 + quad * 4 + r;
                atomicAdd(&Sarr[t * N_SIZE + row], Sp[rt][r]);
            }
    }
}

// Per-class stats + final loss: fused gvec + rowstat. 128 blocks x 256.
// Block c: builds member list of class c, accumulates gS/gT0/gT1 in LDS,
// then computes the 4n loss instances of this class and atomically reduces.
__global__ void classstat_kernel(const __hip_bfloat16* __restrict__ featS,
                                 const __hip_bfloat16* __restrict__ featT0,
                                 const __hip_bfloat16* __restrict__ featT1,
                                 const int* __restrict__ labels,
                                 const float* __restrict__ Sarr,
                                 float* __restrict__ lossAcc,
                                 int* __restrict__ ticket,
                                 float* __restrict__ out) {
    __shared__ int idx[256];
    __shared__ int nsh;
    __shared__ float gS[256], gT0[256], gT1[256];
    __shared__ float wpart[4];

    const int c   = blockIdx.x;
    const int tid = threadIdx.x;
    const int wv  = tid >> 6;
    const int l   = tid & 63;

    if (tid == 0) nsh = 0;
    __syncthreads();
    for (int i = tid; i < B_SIZE; i += 256)
        if ((labels[i] & 127) == c) { int p = atomicAdd(&nsh, 1); idx[p] = i; }
    __syncthreads();
    const int n = nsh;

    if (n > 0) {   // g vectors: thread tid owns dimension tid
        float aS = 0.f, a0 = 0.f, a1 = 0.f;
        for (int m = 0; m < n; ++m) {
            int r = idx[m] * D_SIZE + tid;
            aS += __bfloat162float(featS[r]);
            a0 += __bfloat162float(featT0[r]);
            a1 += __bfloat162float(featT1[r]);
        }
        gS[tid] = aS; gT0[tid] = a0; gT1[tid] = a1;
    }
    __syncthreads();

    float psum = 0.0f;
    const float M = 2.0f * (float)n - 1.0f;
    // instance = m*4 + half*2 + t : row (half? 4096+i : i) of teacher-t problem
    for (int inst = wv; inst < 4 * n; inst += 4) {
        const int t    = inst & 1;
        const int half = (inst >> 1) & 1;
        const int i    = idx[inst >> 2];
        const __hip_bfloat16* f = half ? ((t ? featT1 : featT0) + i * D_SIZE)
                                       : (featS + i * D_SIZE);
        short4v fb = *reinterpret_cast<const short4v*>(f + l * 4);
        const float* gT = t ? gT1 : gT0;
        float dot = 0.f, aii = 0.f;
#pragma unroll
        for (int k = 0; k < 4; ++k) {
            unsigned int u = ((unsigned int)(unsigned short)fb[k]) << 16;
            float fx = __uint_as_float(u);
            dot += fx * (gS[l * 4 + k] + gT[l * 4 + k]);
            aii += fx * fx;
        }
#pragma unroll
        for (int m = 1; m < 64; m <<= 1) {
            dot += __shfl_xor(dot, m);
            aii += __shfl_xor(aii, m);
        }
        if (l == 0) {
            int row = half ? (B_SIZE + i) : i;
            float S = Sarr[t * N_SIZE + row];
            float E = FAST_EXP2(LOG2E10 * aii);
            psum += logf(S - E) - 10.0f * (dot - aii) / M;
        }
    }
    if (l == 0) wpart[wv] = psum;
    __syncthreads();
    if (tid == 0) {
        atomicAdd(lossAcc, wpart[0] + wpart[1] + wpart[2] + wpart[3]);
        __threadfence();
        if (atomicAdd(ticket, 1) == 127) {
            float tot = atomicAdd(lossAcc, 0.0f);   // read-after-all-adds
            out[0] = tot / 16384.0f;
        }
    }
}

extern "C" void kernel_launch(void* const* d_in, const int* in_sizes, int n_in,
                              void* d_out, int out_size, void* d_ws, size_t ws_size,
                              hipStream_t stream) {
    const float* hs     = (const float*)d_in[0];
    const float* ht0    = (const float*)d_in[1];
    const float* ht1    = (const float*)d_in[2];
    const int*   labels = (const int*)d_in[3];

    char* ws = (char*)d_ws;
    float* Sarr    = (float*)(ws);
    float* lossAcc = (float*)(ws + 65536);
    int*   ticket  = (int*)(ws + 65540);
    __hip_bfloat16* featS  = (__hip_bfloat16*)(ws + 524288);
    __hip_bfloat16* featT0 = (__hip_bfloat16*)(ws + 524288 + 2097152);
    __hip_bfloat16* featT1 = (__hip_bfloat16*)(ws + 524288 + 2 * 2097152);

    norm_kernel<<<3072, 256, 0, stream>>>(hs, ht0, ht1, featS, (float*)ws);
    sim_kernel<<<dim3(528, 2), 256, 0, stream>>>(featS, featT0, featT1, Sarr);
    classstat_kernel<<<128, 256, 0, stream>>>(featS, featT0, featT1, labels,
                                              Sarr, lossAcc, ticket, (float*)d_out);
}